// Round 1
// baseline (196.391 us; speedup 1.0000x reference)
//
#include <hip/hip_runtime.h>
#include <stdint.h>

#define BATCH 16
#define CIN   64
#define COUT  64
#define NBR   8
#define HH    128
#define WW    128

// ws layout:
//   [0,          512)      weights  [16][8]  f32
//   [512,        4608)     cbias    [16][64] f32
//   [4608,       1184256)  wfilt    [16][9][64][64] bf16 (as ushort)

typedef __attribute__((ext_vector_type(8)))  short short8;
typedef __attribute__((ext_vector_type(16))) float f32x16;

__device__ __forceinline__ unsigned short f2bf(float f) {
    union { float f; uint32_t u; } v; v.f = f;
    uint32_t u = v.u;
    return (unsigned short)((u + 0x7FFFu + ((u >> 16) & 1u)) >> 16);
}

// ---------------- kernel 1: selector softmax ----------------
__global__ void k_weights(const float* __restrict__ cond,
                          const float* __restrict__ sel_w,
                          const float* __restrict__ sel_b,
                          float* __restrict__ wt) {
    __shared__ float lg[BATCH][NBR];
    int t = threadIdx.x;            // 0..127
    int b = t >> 3, n = t & 7;
    float acc = sel_b[n];
    #pragma unroll
    for (int c = 0; c < CIN; ++c)
        acc += cond[b * CIN + c] * sel_w[n * CIN + c];
    lg[b][n] = acc;
    __syncthreads();
    float m = -1e30f;
    #pragma unroll
    for (int i = 0; i < NBR; ++i) m = fmaxf(m, lg[b][i]);
    float s = 0.f;
    #pragma unroll
    for (int i = 0; i < NBR; ++i) s += __expf(lg[b][i] - m);
    wt[t] = __expf(lg[b][n] - m) / s;
}

// ---------------- kernel 2: fold gate into filter + bias ----------------
// wfilt[b][t][o][c] = sum_n wt[b][n] * filt_w[n][o][c][t]   (bf16)
// cbias[b][o]       = sum_n wt[b][n] * filt_b[n][o]         (f32)
__global__ void k_combine(const float* __restrict__ filt_w,
                          const float* __restrict__ filt_b,
                          const float* __restrict__ wt,
                          unsigned short* __restrict__ wfilt,
                          float* __restrict__ cbias) {
    const int NF = BATCH * 9 * COUT * CIN;          // 589824
    int idx = blockIdx.x * 256 + threadIdx.x;
    if (idx < NF) {
        int c  = idx & 63;
        int o  = (idx >> 6) & 63;
        int bt = idx >> 12;
        int t  = bt % 9;
        int b  = bt / 9;
        float acc = 0.f;
        #pragma unroll
        for (int n = 0; n < NBR; ++n)
            acc += wt[b * NBR + n] * filt_w[((n * COUT + o) * CIN + c) * 9 + t];
        wfilt[idx] = f2bf(acc);
    } else {
        int j = idx - NF;
        if (j < BATCH * COUT) {
            int b = j >> 6, o = j & 63;
            float acc = 0.f;
            #pragma unroll
            for (int n = 0; n < NBR; ++n)
                acc += wt[b * NBR + n] * filt_b[n * COUT + o];
            cbias[j] = acc;
        }
    }
}

// ---------------- kernel 3: per-batch 3x3 conv via implicit-GEMM MFMA ----------------
// block: batch b, 8 output rows, 32 output cols, all 64 couts. 256 thr = 4 waves.
// wave w: rows {2w, 2w+1}; tiles: 2 cout-blocks x 2 row-blocks of 32x32 mfma.
#define RT 8
#define WT 32
#define SLABW 34          // WT + 2 halo
#define SLABR 10          // RT + 2 halo
#define PSTR  68          // channel stride per pixel (64 + 4 pad -> 34 dwords, 2-way banks)

__device__ __forceinline__ short8 lds_frag(const unsigned short* p) {
    union { uint2 u[2]; short8 s; } t;
    t.u[0] = *(const uint2*)p;         // 8B aligned
    t.u[1] = *(const uint2*)(p + 4);
    return t.s;
}
__device__ __forceinline__ short8 gld_frag(const unsigned short* p) {
    union { uint4 u; short8 s; } t;
    t.u = *(const uint4*)p;            // 16B aligned
    return t.s;
}

__global__ __launch_bounds__(256)
void k_conv(const float* __restrict__ x,
            const unsigned short* __restrict__ wfilt,
            const float* __restrict__ cbias,
            float* __restrict__ out) {
    __shared__ unsigned short lx[SLABR * SLABW * PSTR];   // 46240 B
    __shared__ float lbias[COUT];

    const int b  = blockIdx.z;
    const int h0 = blockIdx.y * RT;
    const int w0 = blockIdx.x * WT;
    const int tid = threadIdx.x;

    if (tid < COUT) lbias[tid] = cbias[b * COUT + tid];

    // ---- stage x slab (transposed to channel-last, fp32 -> bf16) ----
    const int NTASK = SLABR * SLABW * 8;     // 2720: (row, wcol, 8-ch group)
    for (int task = tid; task < NTASK; task += 256) {
        int wc  = task % SLABW;
        int pos = task / SLABW;
        int s   = pos % SLABR;
        int cg  = pos / SLABR;               // 0..7
        int hin = h0 + s - 1;
        int win = w0 + wc - 1;
        unsigned short v[8];
        if (hin >= 0 && hin < HH && win >= 0 && win < WW) {
            const float* px = x + (((long)(b * CIN + cg * 8) * HH + hin) * WW + win);
            #pragma unroll
            for (int j = 0; j < 8; ++j) v[j] = f2bf(px[(long)j * HH * WW]);
        } else {
            #pragma unroll
            for (int j = 0; j < 8; ++j) v[j] = 0;
        }
        int base = (s * SLABW + wc) * PSTR + cg * 8;      // *2B -> 8B aligned
        uint2 lo, hi;
        lo.x = (unsigned)v[0] | ((unsigned)v[1] << 16);
        lo.y = (unsigned)v[2] | ((unsigned)v[3] << 16);
        hi.x = (unsigned)v[4] | ((unsigned)v[5] << 16);
        hi.y = (unsigned)v[6] | ((unsigned)v[7] << 16);
        *(uint2*)&lx[base]     = lo;
        *(uint2*)&lx[base + 4] = hi;
    }
    __syncthreads();

    // ---- MFMA main loop ----
    const int lane = tid & 63;
    const int wave = tid >> 6;
    const int l31  = lane & 31;
    const int lh   = lane >> 5;              // 0/1 -> k-half
    const int r0   = wave * 2;               // this wave's 2 output rows

    f32x16 acc00, acc01, acc10, acc11;
    #pragma unroll
    for (int i = 0; i < 16; ++i) { acc00[i] = 0.f; acc01[i] = 0.f; acc10[i] = 0.f; acc11[i] = 0.f; }

    const unsigned short* wf = wfilt + (long)b * 9 * COUT * CIN;

    #pragma unroll
    for (int tap = 0; tap < 9; ++tap) {
        const int kh = tap / 3, kw = tap % 3;
        const unsigned short* wft = wf + (long)tap * COUT * CIN;
        #pragma unroll
        for (int cc = 0; cc < 4; ++cc) {
            const int kofs = cc * 16 + lh * 8;
            // A frags: A[m=cout][k=ch], lane m = l31 (+32 for block 1), k = lh*8 + j
            short8 a0 = gld_frag(wft + (l31)      * CIN + kofs);
            short8 a1 = gld_frag(wft + (32 + l31) * CIN + kofs);
            // B frags: B[k=ch][n=pixel], lane n = l31 -> w = w0 + l31
            short8 b0 = lds_frag(&lx[((r0     + kh) * SLABW + l31 + kw) * PSTR + kofs]);
            short8 b1 = lds_frag(&lx[((r0 + 1 + kh) * SLABW + l31 + kw) * PSTR + kofs]);
            acc00 = __builtin_amdgcn_mfma_f32_32x32x16_bf16(a0, b0, acc00, 0, 0, 0);
            acc01 = __builtin_amdgcn_mfma_f32_32x32x16_bf16(a0, b1, acc01, 0, 0, 0);
            acc10 = __builtin_amdgcn_mfma_f32_32x32x16_bf16(a1, b0, acc10, 0, 0, 0);
            acc11 = __builtin_amdgcn_mfma_f32_32x32x16_bf16(a1, b1, acc11, 0, 0, 0);
        }
    }

    // ---- epilogue: +bias, store fp32 ----
    // D layout (measured m74/m101): col = lane&31 (pixel), row m = (i&3)+8*(i>>2)+4*(lane>>5)
    #pragma unroll
    for (int cb = 0; cb < 2; ++cb) {
        #pragma unroll
        for (int pb = 0; pb < 2; ++pb) {
            const f32x16 v = cb == 0 ? (pb == 0 ? acc00 : acc01)
                                     : (pb == 0 ? acc10 : acc11);
            const int hrow = h0 + r0 + pb;
            float* op = out + (((long)(b * COUT + cb * 32) * HH + hrow) * WW + w0 + l31);
            #pragma unroll
            for (int i = 0; i < 16; ++i) {
                int m = (i & 3) + 8 * (i >> 2) + 4 * lh;
                op[(long)m * HH * WW] = v[i] + lbias[cb * 32 + m];
            }
        }
    }
}

extern "C" void kernel_launch(void* const* d_in, const int* in_sizes, int n_in,
                              void* d_out, int out_size, void* d_ws, size_t ws_size,
                              hipStream_t stream) {
    const float* x      = (const float*)d_in[0];
    const float* cond   = (const float*)d_in[1];
    const float* filt_w = (const float*)d_in[2];
    const float* filt_b = (const float*)d_in[3];
    const float* sel_w  = (const float*)d_in[4];
    const float* sel_b  = (const float*)d_in[5];
    float* out = (float*)d_out;

    float* wt             = (float*)d_ws;
    float* cbias          = (float*)((char*)d_ws + 512);
    unsigned short* wfilt = (unsigned short*)((char*)d_ws + 4608);

    k_weights<<<1, 128, 0, stream>>>(cond, sel_w, sel_b, wt);

    const int NF = BATCH * 9 * COUT * CIN + BATCH * COUT;   // 590848
    k_combine<<<(NF + 255) / 256, 256, 0, stream>>>(filt_w, filt_b, wt, wfilt, cbias);

    dim3 grid(WW / WT, HH / RT, BATCH);                      // 4 x 16 x 16
    k_conv<<<grid, 256, 0, stream>>>(x, wfilt, cbias, out);
}